// Round 15
// baseline (137.168 us; speedup 1.0000x reference)
//
#include <hip/hip_runtime.h>

typedef __attribute__((ext_vector_type(8)))  short short8;
typedef __attribute__((ext_vector_type(16))) float f32x16;

#define B_SZ  16
#define NPTS  4096
#define MBLK  256                   // 4 waves
#define PRB   256                   // pred rows per block (64/wave, 2x32 frags)
#define NFR   2
#define NCH   (NPTS / PRB)          // 16 row-chunks
#define NQ    4                     // target quarters
#define QTGT  (NPTS / NQ)           // 1024 targets per block
#define STGT  512                   // targets per LDS stage
#define STILE (STGT / 32)           // 16 tiles per stage
#define NSTG  (QTGT / STGT)         // 2 stages
#define NRT   (B_SZ * NPTS)         // 65536 rows (= cols) total
#define BLK   256

__device__ __forceinline__ unsigned short f2bf(float f) {
    unsigned u = __float_as_uint(f);
    return (unsigned short)((u + 0x7FFFu + ((u >> 16) & 1u)) >> 16);
}
__device__ __forceinline__ float bf2f(unsigned short s) {
    return __uint_as_float(((unsigned)s) << 16);
}
__device__ __forceinline__ short n2(unsigned short s) {
    return (short)f2bf(-2.0f * bf2f(s));
}
// NOTE: no min3f inline-asm anywhere in this file. Every round that applied
// the asm min3 to MFMA result registers failed (R10/R13/R14); every round
// using plain fminf on them passed (R9/R11/R12). Suspected "v"-constraint
// mis-handling of AGPR-resident values on the unified gfx950 file.

// ---------------------------------------------------------------------------
// Single-pass chamfer (R14 structure). ONE change vs R14: the col-side
// reduction is a balanced fminf tree (compiler v_min_f32, the proven
// primitive) instead of the inline-asm min3 tree. Everything else verbatim:
//  - slot algebra s0-2:-2ph·th s3-5:-2pl·th s6-8:-2ph·tl s9-11:-2pl·tl
//    s12,13:p2h,p2l s14,15:t2h,t2l (absmax 0.0 at R9/R11/R12)
//  - row path: register fmin fold + shfl_xor(1..16) + label write (R12)
//  - col path: per-(tile,lane) fold + DIRECT global uint atomicMin (R4-R7)
//  - probes verify row/col groupings; label-indexed slow path otherwise
// ---------------------------------------------------------------------------
__global__ __launch_bounds__(MBLK, 2) void chamfer_mfma(
    const float* __restrict__ pred, const float* __restrict__ target,
    float* __restrict__ wsRow, unsigned* __restrict__ wsCol)
{
    __shared__ short8   sB[STILE * 64];   // 16 KB B fragments
    __shared__ unsigned rowLds[MBLK];     // slow-path row mins only

    const int bx    = blockIdx.x;               // [0,1024)
    const int b     = bx >> 6;                  // 64 blocks per batch
    const int chunk = (bx >> 2) & (NCH - 1);
    const int q     = bx & (NQ - 1);
    const int tid   = threadIdx.x;
    const int lane  = tid & 63;
    const int w     = tid >> 6;
    const int r32   = lane & 31;
    const int h     = lane >> 5;
    const short ONE = (short)0x3F80;

    // ---- A fragments: 2 x 32 pred rows per wave (R12 verbatim) ----
    short8 af[NFR];
    #pragma unroll
    for (int f = 0; f < NFR; ++f) {
        const float* pp = pred +
            ((size_t)b*NPTS + chunk*PRB + w*64 + f*32 + r32)*3;
        float x = pp[0], y = pp[1], z = pp[2];
        unsigned short phx=f2bf(x), phy=f2bf(y), phz=f2bf(z);
        unsigned short plx=f2bf(x-bf2f(phx)), ply=f2bf(y-bf2f(phy)),
                       plz=f2bf(z-bf2f(phz));
        short8 v;
        if (h == 0) {
            v[0]=n2(phx); v[1]=n2(phy); v[2]=n2(phz);
            v[3]=n2(plx); v[4]=n2(ply); v[5]=n2(plz);
            v[6]=n2(phx); v[7]=n2(phy);
        } else {
            float p2 = fmaf(z,z,fmaf(y,y,x*x));
            unsigned short p2h=f2bf(p2), p2l=f2bf(p2-bf2f(p2h));
            v[0]=n2(phz); v[1]=n2(plx); v[2]=n2(ply); v[3]=n2(plz);
            v[4]=(short)p2h; v[5]=(short)p2l; v[6]=ONE; v[7]=ONE;
        }
        af[f] = v;
    }

    f32x16 zc;
    #pragma unroll
    for (int r = 0; r < 16; ++r) zc[r] = 0.0f;

    // ---- probes: row labels (A-marker) and col labels (B-marker) ----
    int lab[16], clab[16];
    bool okR = true, okC = true;
    {
        short8 mA = {0,0,0,0,0,0,0,0}, mB = {0,0,0,0,0,0,0,0};
        if (h == 0) { mA[0] = (short)f2bf((float)r32); mB[0] = ONE; }
        f32x16 p1 = __builtin_amdgcn_mfma_f32_32x32x16_bf16(mA, mB, zc, 0,0,0);
        short8 nA = {0,0,0,0,0,0,0,0}, nB = {0,0,0,0,0,0,0,0};
        if (h == 0) { nA[0] = ONE; nB[0] = (short)f2bf((float)r32); }
        f32x16 p2 = __builtin_amdgcn_mfma_f32_32x32x16_bf16(nA, nB, zc, 0,0,0);
        #pragma unroll
        for (int r = 0; r < 16; ++r) {
            lab[r]  = ((int)(p1[r] + 0.5f)) & 31;
            clab[r] = ((int)(p2[r] + 0.5f)) & 31;
            okR = okR && (lab[r]  == ((r&3) + 8*(r>>2) + 4*h));
            okC = okC && (clab[r] == r32);
        }
    }
    const bool fast = __all(okR && okC) != 0;

    const float* tgtB = target + ((size_t)b * NPTS + q * QTGT) * 3;
    unsigned*    wcq  = wsCol + (size_t)b * NPTS + q * QTGT;

    f32x16 rmin0, rmin1;
    #pragma unroll
    for (int r = 0; r < 16; ++r) { rmin0[r] = 1e30f; rmin1[r] = 1e30f; }

    if (fast) {
        for (int s = 0; s < NSTG; ++s) {
            __syncthreads();
            // ---- stage 512 targets as B fragments (R12 verbatim) ----
            #pragma unroll
            for (int i = 0; i < (STILE*64)/MBLK; ++i) {   // 4 entries/thread
                int e  = i * MBLK + tid;
                int t  = e >> 6, l2 = e & 63;
                int cc = l2 & 31, hh = l2 >> 5;
                const float* o = tgtB + (size_t)(s*STGT + t*32 + cc)*3;
                float tx=o[0], ty=o[1], tz=o[2];
                unsigned short hx=f2bf(tx), hy=f2bf(ty), hz=f2bf(tz);
                unsigned short lx=f2bf(tx-bf2f(hx)), ly=f2bf(ty-bf2f(hy)),
                               lz=f2bf(tz-bf2f(hz));
                short8 v;
                if (hh == 0) {
                    v[0]=(short)hx; v[1]=(short)hy; v[2]=(short)hz;
                    v[3]=(short)hx; v[4]=(short)hy; v[5]=(short)hz;
                    v[6]=(short)lx; v[7]=(short)ly;
                } else {
                    float t2 = fmaf(tz,tz,fmaf(ty,ty,tx*tx));
                    unsigned short t2h=f2bf(t2), t2l=f2bf(t2-bf2f(t2h));
                    v[0]=(short)lz; v[1]=(short)lx; v[2]=(short)ly;
                    v[3]=(short)lz; v[4]=ONE; v[5]=ONE;
                    v[6]=(short)t2h; v[7]=(short)t2l;
                }
                sB[e] = v;
            }
            __syncthreads();

            for (int t = 0; t < STILE; ++t) {
                short8 b0 = sB[t*64 + lane];
                f32x16 a0 = __builtin_amdgcn_mfma_f32_32x32x16_bf16(af[0], b0, zc, 0,0,0);
                f32x16 a1 = __builtin_amdgcn_mfma_f32_32x32x16_bf16(af[1], b0, zc, 0,0,0);
                // row path: fold into registers (R12-proven)
                #pragma unroll
                for (int r = 0; r < 16; ++r) {
                    rmin0[r] = fminf(a0[r], rmin0[r]);
                    rmin1[r] = fminf(a1[r], rmin1[r]);
                }
                // col path: balanced fminf tree over the lane's 32 result
                // regs (rows {pat}+4h of both fragments; lane l^32 covers
                // the complementary rows; global atomicMin merges halves)
                float cm[16];
                #pragma unroll
                for (int r = 0; r < 16; ++r) cm[r] = fminf(a0[r], a1[r]);
                #pragma unroll
                for (int d2 = 8; d2 > 0; d2 >>= 1) {
                    #pragma unroll
                    for (int r = 0; r < 8; ++r)
                        if (r < d2) cm[r] = fminf(cm[r], cm[r + d2]);
                }
                // PROVEN primitive: global uint atomicMin (R4-R7)
                atomicMin(&wcq[s*STGT + t*32 + r32],
                          __float_as_uint(fmaxf(cm[0], 0.0f)));
            }
        }

        // ---- row epilogue (R12 verbatim): shfl fold, write by LABEL ----
        float* wr = wsRow + (size_t)q * NRT + (size_t)b * NPTS + chunk * PRB;
        #pragma unroll
        for (int r = 0; r < 16; ++r) {
            float v0 = rmin0[r];
            v0 = fminf(v0, __shfl_xor(v0, 1, 64));
            v0 = fminf(v0, __shfl_xor(v0, 2, 64));
            v0 = fminf(v0, __shfl_xor(v0, 4, 64));
            v0 = fminf(v0, __shfl_xor(v0, 8, 64));
            v0 = fminf(v0, __shfl_xor(v0, 16, 64));
            float v1 = rmin1[r];
            v1 = fminf(v1, __shfl_xor(v1, 1, 64));
            v1 = fminf(v1, __shfl_xor(v1, 2, 64));
            v1 = fminf(v1, __shfl_xor(v1, 4, 64));
            v1 = fminf(v1, __shfl_xor(v1, 8, 64));
            v1 = fminf(v1, __shfl_xor(v1, 16, 64));
            if (r32 == 0) {
                wr[w*64 +  0 + lab[r]] = v0;
                wr[w*64 + 32 + lab[r]] = v1;
            }
        }
    } else {
        // ---- slow, layout-agnostic loop: everything by probed label ----
        rowLds[tid] = 0x7F7F7F7Fu;

        for (int s = 0; s < NSTG; ++s) {
            __syncthreads();
            #pragma unroll
            for (int i = 0; i < (STILE*64)/MBLK; ++i) {
                int e  = i * MBLK + tid;
                int t  = e >> 6, l2 = e & 63;
                int cc = l2 & 31, hh = l2 >> 5;
                const float* o = tgtB + (size_t)(s*STGT + t*32 + cc)*3;
                float tx=o[0], ty=o[1], tz=o[2];
                unsigned short hx=f2bf(tx), hy=f2bf(ty), hz=f2bf(tz);
                unsigned short lx=f2bf(tx-bf2f(hx)), ly=f2bf(ty-bf2f(hy)),
                               lz=f2bf(tz-bf2f(hz));
                short8 v;
                if (hh == 0) {
                    v[0]=(short)hx; v[1]=(short)hy; v[2]=(short)hz;
                    v[3]=(short)hx; v[4]=(short)hy; v[5]=(short)hz;
                    v[6]=(short)lx; v[7]=(short)ly;
                } else {
                    float t2 = fmaf(tz,tz,fmaf(ty,ty,tx*tx));
                    unsigned short t2h=f2bf(t2), t2l=f2bf(t2-bf2f(t2h));
                    v[0]=(short)lz; v[1]=(short)lx; v[2]=(short)ly;
                    v[3]=(short)lz; v[4]=ONE; v[5]=ONE;
                    v[6]=(short)t2h; v[7]=(short)t2l;
                }
                sB[e] = v;
            }
            __syncthreads();

            for (int t = 0; t < STILE; ++t) {
                short8 b0 = sB[t*64 + lane];
                f32x16 a0 = __builtin_amdgcn_mfma_f32_32x32x16_bf16(af[0], b0, zc, 0,0,0);
                f32x16 a1 = __builtin_amdgcn_mfma_f32_32x32x16_bf16(af[1], b0, zc, 0,0,0);
                #pragma unroll
                for (int r = 0; r < 16; ++r) {
                    unsigned u0 = __float_as_uint(fmaxf(a0[r], 0.0f));
                    unsigned u1 = __float_as_uint(fmaxf(a1[r], 0.0f));
                    atomicMin(&rowLds[w*64 +  0 + lab[r]], u0);
                    atomicMin(&rowLds[w*64 + 32 + lab[r]], u1);
                    atomicMin(&wcq[s*STGT + t*32 + clab[r]], u0);  // global
                    atomicMin(&wcq[s*STGT + t*32 + clab[r]], u1);  // global
                }
            }
        }
        __syncthreads();
        float* wr = wsRow + (size_t)q * NRT + (size_t)b * NPTS + chunk * PRB;
        wr[tid] = __uint_as_float(rowLds[tid]);
    }
}

// -------- combine: rows fold 4 quarters, cols direct; mean-reduce -----------
__global__ __launch_bounds__(BLK) void chamfer_combine(
    const float* __restrict__ wsRow, const unsigned* __restrict__ wsCol,
    float* __restrict__ out)
{
    const int idx = blockIdx.x * BLK + threadIdx.x;   // 0 .. 131071
    float v;
    if (idx < NRT) {
        v = fminf(fminf(wsRow[idx],         wsRow[NRT + idx]),
                  fminf(wsRow[2*NRT + idx], wsRow[3*NRT + idx]));
    } else {
        v = __uint_as_float(wsCol[idx - NRT]);
    }

    for (int off = 32; off > 0; off >>= 1)
        v += __shfl_down(v, off, 64);

    __shared__ float red[4];
    const int tid = threadIdx.x;
    if ((tid & 63) == 0) red[tid >> 6] = v;
    __syncthreads();
    if (tid == 0) {
        float s = (red[0] + red[1]) + (red[2] + red[3]);
        atomicAdd(out, s * (1.0f / (float)NRT));
    }
}

// ---------------- fallback (round-1 kernel) if ws too small ------------------
__global__ __launch_bounds__(BLK) void chamfer_kernel(
    const float* __restrict__ pred, const float* __restrict__ target,
    float* __restrict__ out)
{
    __shared__ float4 sOpp[NPTS];

    const int dir = blockIdx.y;
    const float* own = (dir == 0) ? pred : target;
    const float* opp = (dir == 0) ? target : pred;

    const int b     = blockIdx.x >> 4;
    const int chunk = blockIdx.x & 15;
    const int tid   = threadIdx.x;

    const float* oppB = opp + (size_t)b * NPTS * 3;
    for (int j = tid; j < NPTS; j += BLK) {
        float x = oppB[3 * j + 0];
        float y = oppB[3 * j + 1];
        float z = oppB[3 * j + 2];
        sOpp[j] = make_float4(-2.0f * x, -2.0f * y, -2.0f * z,
                              fmaf(z, z, fmaf(y, y, x * x)));
    }
    __syncthreads();

    const int i = chunk * BLK + tid;
    const float* op = own + ((size_t)b * NPTS + i) * 3;
    const float px = op[0], py = op[1], pz = op[2];
    const float p2 = fmaf(pz, pz, fmaf(py, py, px * px));

    float m0 = 1e30f, m1 = 1e30f, m2 = 1e30f, m3 = 1e30f;
    for (int j = 0; j < NPTS; j += 8) {
        float4 t0 = sOpp[j + 0];
        float4 t1 = sOpp[j + 1];
        float4 t2 = sOpp[j + 2];
        float4 t3 = sOpp[j + 3];
        float4 t4 = sOpp[j + 4];
        float4 t5 = sOpp[j + 5];
        float4 t6 = sOpp[j + 6];
        float4 t7 = sOpp[j + 7];
        m0 = fminf(m0, fmaf(t0.x, px, fmaf(t0.y, py, fmaf(t0.z, pz, t0.w))));
        m1 = fminf(m1, fmaf(t1.x, px, fmaf(t1.y, py, fmaf(t1.z, pz, t1.w))));
        m2 = fminf(m2, fmaf(t2.x, px, fmaf(t2.y, py, fmaf(t2.z, pz, t2.w))));
        m3 = fminf(m3, fmaf(t3.x, px, fmaf(t3.y, py, fmaf(t3.z, pz, t3.w))));
        m0 = fminf(m0, fmaf(t4.x, px, fmaf(t4.y, py, fmaf(t4.z, pz, t4.w))));
        m1 = fminf(m1, fmaf(t5.x, px, fmaf(t5.y, py, fmaf(t5.z, pz, t5.w))));
        m2 = fminf(m2, fmaf(t6.x, px, fmaf(t6.y, py, fmaf(t6.z, pz, t6.w))));
        m3 = fminf(m3, fmaf(t7.x, px, fmaf(t7.y, py, fmaf(t7.z, pz, t7.w))));
    }
    float v = fminf(fminf(m0, m1), fminf(m2, m3)) + p2;

    for (int off = 32; off > 0; off >>= 1)
        v += __shfl_down(v, off, 64);

    __syncthreads();
    float* red = (float*)sOpp;
    if ((tid & 63) == 0) red[tid >> 6] = v;
    __syncthreads();
    if (tid == 0) {
        float s = (red[0] + red[1]) + (red[2] + red[3]);
        atomicAdd(out, s * (1.0f / ((float)B_SZ * (float)NPTS)));
    }
}

extern "C" void kernel_launch(void* const* d_in, const int* in_sizes, int n_in,
                              void* d_out, int out_size, void* d_ws, size_t ws_size,
                              hipStream_t stream) {
    const float* pred   = (const float*)d_in[0];
    const float* target = (const float*)d_in[1];
    float* out = (float*)d_out;

    hipMemsetAsync(out, 0, sizeof(float), stream);

    const size_t rowBytes = (size_t)NQ * NRT * sizeof(float);   // 1 MB
    const size_t colBytes = (size_t)NRT * sizeof(unsigned);     // 256 KB
    if (ws_size >= rowBytes + colBytes) {
        float*    wsRow = (float*)d_ws;
        unsigned* wsCol = (unsigned*)((char*)d_ws + rowBytes);
        hipMemsetAsync(wsCol, 0x7F, colBytes, stream);  // +inf-ish sentinel
        chamfer_mfma<<<B_SZ * NCH * NQ, MBLK, 0, stream>>>(pred, target,
                                                           wsRow, wsCol);
        chamfer_combine<<<(2 * NRT) / BLK, BLK, 0, stream>>>(wsRow, wsCol, out);
    } else {
        dim3 grid(B_SZ * (NPTS / BLK), 2);
        chamfer_kernel<<<grid, BLK, 0, stream>>>(pred, target, out);
    }
}

// Round 16
// 63.157 us; speedup vs baseline: 2.1719x; 2.1719x over previous
//
#include <hip/hip_runtime.h>

typedef __attribute__((ext_vector_type(8)))  short short8;
typedef __attribute__((ext_vector_type(16))) float f32x16;

#define B_SZ  16
#define NPTS  4096
#define MBLK  256                   // 4 waves
#define PRB   256                   // pred rows per block (64/wave, 2x32 frags)
#define NFR   2
#define NCH   (NPTS / PRB)          // 16 row-chunks
#define NQ    4                     // target quarters
#define QTGT  (NPTS / NQ)           // 1024 targets per block
#define STGT  512                   // targets per LDS stage
#define STILE (STGT / 32)           // 16 tiles per stage
#define NSTG  (QTGT / STGT)         // 2 stages
#define NRT   (B_SZ * NPTS)         // 65536 rows (= cols) total
#define BLK   256

__device__ __forceinline__ unsigned short f2bf(float f) {
    unsigned u = __float_as_uint(f);
    return (unsigned short)((u + 0x7FFFu + ((u >> 16) & 1u)) >> 16);
}
__device__ __forceinline__ float bf2f(unsigned short s) {
    return __uint_as_float(((unsigned)s) << 16);
}
__device__ __forceinline__ short n2(unsigned short s) {
    return (short)f2bf(-2.0f * bf2f(s));
}
// NOTE: no min3f inline-asm. R10/R13/R14 (asm min3 on MFMA results) all
// failed; R15 (fminf only) passed -- confirmed culprit. Never reintroduce.

// ---------------------------------------------------------------------------
// Single-pass chamfer (R15-passing core). ONE structural change vs R15: the
// col-side global atomicMin storm (50 MB/dispatch write traffic, 137 us) is
// replaced by contention-free aggregation:
//   per tile: shfl_xor(32) merges the two k-half lanes; one lane plain-stores
//   the per-wave col partial to LDS colWu[4][QTGT] (each entry written once);
//   block epilogue folds 4 waves and plain-stores 1024 values to a per-chunk
//   slice wsColPart[16][NRT]; combine kernel min-folds the 16 slices.
// Atomic-mode fallback (ws too small) and label-indexed slow path retained.
// Slot algebra / staging / probes / row path: R15 verbatim (absmax 0.0).
// ---------------------------------------------------------------------------
__global__ __launch_bounds__(MBLK, 2) void chamfer_mfma(
    const float* __restrict__ pred, const float* __restrict__ target,
    float* __restrict__ wsRow, unsigned* __restrict__ wsCol,
    unsigned* __restrict__ wsColPart)
{
    __shared__ short8   sB[STILE * 64];   // 16 KB B fragments
    __shared__ unsigned colWu[4 * QTGT];  // 16 KB per-wave col partials
    __shared__ unsigned rowLds[MBLK];     // slow-path row mins only

    const int bx    = blockIdx.x;               // [0,1024)
    const int b     = bx >> 6;                  // 64 blocks per batch
    const int chunk = (bx >> 2) & (NCH - 1);
    const int q     = bx & (NQ - 1);
    const int tid   = threadIdx.x;
    const int lane  = tid & 63;
    const int w     = tid >> 6;
    const int r32   = lane & 31;
    const int h     = lane >> 5;
    const short ONE = (short)0x3F80;

    // ---- A fragments: 2 x 32 pred rows per wave (R12 verbatim) ----
    short8 af[NFR];
    #pragma unroll
    for (int f = 0; f < NFR; ++f) {
        const float* pp = pred +
            ((size_t)b*NPTS + chunk*PRB + w*64 + f*32 + r32)*3;
        float x = pp[0], y = pp[1], z = pp[2];
        unsigned short phx=f2bf(x), phy=f2bf(y), phz=f2bf(z);
        unsigned short plx=f2bf(x-bf2f(phx)), ply=f2bf(y-bf2f(phy)),
                       plz=f2bf(z-bf2f(phz));
        short8 v;
        if (h == 0) {
            v[0]=n2(phx); v[1]=n2(phy); v[2]=n2(phz);
            v[3]=n2(plx); v[4]=n2(ply); v[5]=n2(plz);
            v[6]=n2(phx); v[7]=n2(phy);
        } else {
            float p2 = fmaf(z,z,fmaf(y,y,x*x));
            unsigned short p2h=f2bf(p2), p2l=f2bf(p2-bf2f(p2h));
            v[0]=n2(phz); v[1]=n2(plx); v[2]=n2(ply); v[3]=n2(plz);
            v[4]=(short)p2h; v[5]=(short)p2l; v[6]=ONE; v[7]=ONE;
        }
        af[f] = v;
    }

    f32x16 zc;
    #pragma unroll
    for (int r = 0; r < 16; ++r) zc[r] = 0.0f;

    // ---- probes: row labels (A-marker) and col labels (B-marker) ----
    int lab[16], clab[16];
    bool okR = true, okC = true;
    {
        short8 mA = {0,0,0,0,0,0,0,0}, mB = {0,0,0,0,0,0,0,0};
        if (h == 0) { mA[0] = (short)f2bf((float)r32); mB[0] = ONE; }
        f32x16 p1 = __builtin_amdgcn_mfma_f32_32x32x16_bf16(mA, mB, zc, 0,0,0);
        short8 nA = {0,0,0,0,0,0,0,0}, nB = {0,0,0,0,0,0,0,0};
        if (h == 0) { nA[0] = ONE; nB[0] = (short)f2bf((float)r32); }
        f32x16 p2 = __builtin_amdgcn_mfma_f32_32x32x16_bf16(nA, nB, zc, 0,0,0);
        #pragma unroll
        for (int r = 0; r < 16; ++r) {
            lab[r]  = ((int)(p1[r] + 0.5f)) & 31;
            clab[r] = ((int)(p2[r] + 0.5f)) & 31;
            okR = okR && (lab[r]  == ((r&3) + 8*(r>>2) + 4*h));
            okC = okC && (clab[r] == r32);
        }
    }
    const bool fast = __all(okR && okC) != 0;

    // sentinel init (needed by slow path; fast path overwrites every entry)
    for (int i = tid; i < 4 * QTGT; i += MBLK) colWu[i] = 0x7F7F7F7Fu;

    const float* tgtB = target + ((size_t)b * NPTS + q * QTGT) * 3;

    f32x16 rmin0, rmin1;
    #pragma unroll
    for (int r = 0; r < 16; ++r) { rmin0[r] = 1e30f; rmin1[r] = 1e30f; }

    if (fast) {
        for (int s = 0; s < NSTG; ++s) {
            __syncthreads();
            // ---- stage 512 targets as B fragments (R12 verbatim) ----
            #pragma unroll
            for (int i = 0; i < (STILE*64)/MBLK; ++i) {   // 4 entries/thread
                int e  = i * MBLK + tid;
                int t  = e >> 6, l2 = e & 63;
                int cc = l2 & 31, hh = l2 >> 5;
                const float* o = tgtB + (size_t)(s*STGT + t*32 + cc)*3;
                float tx=o[0], ty=o[1], tz=o[2];
                unsigned short hx=f2bf(tx), hy=f2bf(ty), hz=f2bf(tz);
                unsigned short lx=f2bf(tx-bf2f(hx)), ly=f2bf(ty-bf2f(hy)),
                               lz=f2bf(tz-bf2f(hz));
                short8 v;
                if (hh == 0) {
                    v[0]=(short)hx; v[1]=(short)hy; v[2]=(short)hz;
                    v[3]=(short)hx; v[4]=(short)hy; v[5]=(short)hz;
                    v[6]=(short)lx; v[7]=(short)ly;
                } else {
                    float t2 = fmaf(tz,tz,fmaf(ty,ty,tx*tx));
                    unsigned short t2h=f2bf(t2), t2l=f2bf(t2-bf2f(t2h));
                    v[0]=(short)lz; v[1]=(short)lx; v[2]=(short)ly;
                    v[3]=(short)lz; v[4]=ONE; v[5]=ONE;
                    v[6]=(short)t2h; v[7]=(short)t2l;
                }
                sB[e] = v;
            }
            __syncthreads();

            for (int t = 0; t < STILE; ++t) {
                short8 b0 = sB[t*64 + lane];
                f32x16 a0 = __builtin_amdgcn_mfma_f32_32x32x16_bf16(af[0], b0, zc, 0,0,0);
                f32x16 a1 = __builtin_amdgcn_mfma_f32_32x32x16_bf16(af[1], b0, zc, 0,0,0);
                // row path: fold into registers (R12-proven)
                #pragma unroll
                for (int r = 0; r < 16; ++r) {
                    rmin0[r] = fminf(a0[r], rmin0[r]);
                    rmin1[r] = fminf(a1[r], rmin1[r]);
                }
                // col path: balanced fminf tree (proven R15), then merge the
                // two k-half lanes and plain-store the per-wave partial
                float cm[16];
                #pragma unroll
                for (int r = 0; r < 16; ++r) cm[r] = fminf(a0[r], a1[r]);
                #pragma unroll
                for (int d2 = 8; d2 > 0; d2 >>= 1) {
                    #pragma unroll
                    for (int r = 0; r < 8; ++r)
                        if (r < d2) cm[r] = fminf(cm[r], cm[r + d2]);
                }
                float cmv = fminf(cm[0], __shfl_xor(cm[0], 32, 64));
                if (h == 0)   // one writer per (wave, col): plain LDS store
                    colWu[w*QTGT + s*STGT + t*32 + r32] =
                        __float_as_uint(fmaxf(cmv, 0.0f));
            }
        }

        // ---- row epilogue (R12 verbatim): shfl fold, write by LABEL ----
        float* wr = wsRow + (size_t)q * NRT + (size_t)b * NPTS + chunk * PRB;
        #pragma unroll
        for (int r = 0; r < 16; ++r) {
            float v0 = rmin0[r];
            v0 = fminf(v0, __shfl_xor(v0, 1, 64));
            v0 = fminf(v0, __shfl_xor(v0, 2, 64));
            v0 = fminf(v0, __shfl_xor(v0, 4, 64));
            v0 = fminf(v0, __shfl_xor(v0, 8, 64));
            v0 = fminf(v0, __shfl_xor(v0, 16, 64));
            float v1 = rmin1[r];
            v1 = fminf(v1, __shfl_xor(v1, 1, 64));
            v1 = fminf(v1, __shfl_xor(v1, 2, 64));
            v1 = fminf(v1, __shfl_xor(v1, 4, 64));
            v1 = fminf(v1, __shfl_xor(v1, 8, 64));
            v1 = fminf(v1, __shfl_xor(v1, 16, 64));
            if (r32 == 0) {
                wr[w*64 +  0 + lab[r]] = v0;
                wr[w*64 + 32 + lab[r]] = v1;
            }
        }
    } else {
        // ---- slow, layout-agnostic loop: everything by probed label ----
        rowLds[tid] = 0x7F7F7F7Fu;

        for (int s = 0; s < NSTG; ++s) {
            __syncthreads();
            #pragma unroll
            for (int i = 0; i < (STILE*64)/MBLK; ++i) {
                int e  = i * MBLK + tid;
                int t  = e >> 6, l2 = e & 63;
                int cc = l2 & 31, hh = l2 >> 5;
                const float* o = tgtB + (size_t)(s*STGT + t*32 + cc)*3;
                float tx=o[0], ty=o[1], tz=o[2];
                unsigned short hx=f2bf(tx), hy=f2bf(ty), hz=f2bf(tz);
                unsigned short lx=f2bf(tx-bf2f(hx)), ly=f2bf(ty-bf2f(hy)),
                               lz=f2bf(tz-bf2f(hz));
                short8 v;
                if (hh == 0) {
                    v[0]=(short)hx; v[1]=(short)hy; v[2]=(short)hz;
                    v[3]=(short)hx; v[4]=(short)hy; v[5]=(short)hz;
                    v[6]=(short)lx; v[7]=(short)ly;
                } else {
                    float t2 = fmaf(tz,tz,fmaf(ty,ty,tx*tx));
                    unsigned short t2h=f2bf(t2), t2l=f2bf(t2-bf2f(t2h));
                    v[0]=(short)lz; v[1]=(short)lx; v[2]=(short)ly;
                    v[3]=(short)lz; v[4]=ONE; v[5]=ONE;
                    v[6]=(short)t2h; v[7]=(short)t2l;
                }
                sB[e] = v;
            }
            __syncthreads();

            for (int t = 0; t < STILE; ++t) {
                short8 b0 = sB[t*64 + lane];
                f32x16 a0 = __builtin_amdgcn_mfma_f32_32x32x16_bf16(af[0], b0, zc, 0,0,0);
                f32x16 a1 = __builtin_amdgcn_mfma_f32_32x32x16_bf16(af[1], b0, zc, 0,0,0);
                #pragma unroll
                for (int r = 0; r < 16; ++r) {
                    unsigned u0 = __float_as_uint(fmaxf(a0[r], 0.0f));
                    unsigned u1 = __float_as_uint(fmaxf(a1[r], 0.0f));
                    atomicMin(&rowLds[w*64 +  0 + lab[r]], u0);
                    atomicMin(&rowLds[w*64 + 32 + lab[r]], u1);
                    atomicMin(&colWu[w*QTGT + s*STGT + t*32 + clab[r]], u0);
                    atomicMin(&colWu[w*QTGT + s*STGT + t*32 + clab[r]], u1);
                }
            }
        }
        __syncthreads();
        float* wr = wsRow + (size_t)q * NRT + (size_t)b * NPTS + chunk * PRB;
        wr[tid] = __uint_as_float(rowLds[tid]);
    }

    // ---- col epilogue: fold 4 wave slices; slice store OR atomic mode ----
    __syncthreads();
    for (int c = tid; c < QTGT; c += MBLK) {
        unsigned v = min(min(colWu[c],          colWu[QTGT + c]),
                         min(colWu[2*QTGT + c], colWu[3*QTGT + c]));
        if (wsColPart)
            wsColPart[((size_t)chunk * B_SZ + b) * NPTS + q * QTGT + c] = v;
        else
            atomicMin(&wsCol[(size_t)b * NPTS + q * QTGT + c], v);
    }
}

// -------- combine: rows fold 4 q-slices; cols fold 16 chunk-slices ----------
__global__ __launch_bounds__(BLK) void chamfer_combine(
    const float* __restrict__ wsRow, const unsigned* __restrict__ wsCol,
    const unsigned* __restrict__ wsColPart, float* __restrict__ out)
{
    const int idx = blockIdx.x * BLK + threadIdx.x;   // 0 .. 131071
    float v;
    if (idx < NRT) {
        v = fminf(fminf(wsRow[idx],         wsRow[NRT + idx]),
                  fminf(wsRow[2*NRT + idx], wsRow[3*NRT + idx]));
    } else {
        const int c = idx - NRT;
        if (wsColPart) {
            unsigned m = 0x7F7F7F7Fu;
            #pragma unroll
            for (int k = 0; k < NCH; ++k)
                m = min(m, wsColPart[(size_t)k * NRT + c]);
            v = __uint_as_float(m);
        } else {
            v = __uint_as_float(wsCol[c]);
        }
    }

    for (int off = 32; off > 0; off >>= 1)
        v += __shfl_down(v, off, 64);

    __shared__ float red[4];
    const int tid = threadIdx.x;
    if ((tid & 63) == 0) red[tid >> 6] = v;
    __syncthreads();
    if (tid == 0) {
        float s = (red[0] + red[1]) + (red[2] + red[3]);
        atomicAdd(out, s * (1.0f / (float)NRT));
    }
}

// ---------------- fallback (round-1 kernel) if ws too small ------------------
__global__ __launch_bounds__(BLK) void chamfer_kernel(
    const float* __restrict__ pred, const float* __restrict__ target,
    float* __restrict__ out)
{
    __shared__ float4 sOpp[NPTS];

    const int dir = blockIdx.y;
    const float* own = (dir == 0) ? pred : target;
    const float* opp = (dir == 0) ? target : pred;

    const int b     = blockIdx.x >> 4;
    const int chunk = blockIdx.x & 15;
    const int tid   = threadIdx.x;

    const float* oppB = opp + (size_t)b * NPTS * 3;
    for (int j = tid; j < NPTS; j += BLK) {
        float x = oppB[3 * j + 0];
        float y = oppB[3 * j + 1];
        float z = oppB[3 * j + 2];
        sOpp[j] = make_float4(-2.0f * x, -2.0f * y, -2.0f * z,
                              fmaf(z, z, fmaf(y, y, x * x)));
    }
    __syncthreads();

    const int i = chunk * BLK + tid;
    const float* op = own + ((size_t)b * NPTS + i) * 3;
    const float px = op[0], py = op[1], pz = op[2];
    const float p2 = fmaf(pz, pz, fmaf(py, py, px * px));

    float m0 = 1e30f, m1 = 1e30f, m2 = 1e30f, m3 = 1e30f;
    for (int j = 0; j < NPTS; j += 8) {
        float4 t0 = sOpp[j + 0];
        float4 t1 = sOpp[j + 1];
        float4 t2 = sOpp[j + 2];
        float4 t3 = sOpp[j + 3];
        float4 t4 = sOpp[j + 4];
        float4 t5 = sOpp[j + 5];
        float4 t6 = sOpp[j + 6];
        float4 t7 = sOpp[j + 7];
        m0 = fminf(m0, fmaf(t0.x, px, fmaf(t0.y, py, fmaf(t0.z, pz, t0.w))));
        m1 = fminf(m1, fmaf(t1.x, px, fmaf(t1.y, py, fmaf(t1.z, pz, t1.w))));
        m2 = fminf(m2, fmaf(t2.x, px, fmaf(t2.y, py, fmaf(t2.z, pz, t2.w))));
        m3 = fminf(m3, fmaf(t3.x, px, fmaf(t3.y, py, fmaf(t3.z, pz, t3.w))));
        m0 = fminf(m0, fmaf(t4.x, px, fmaf(t4.y, py, fmaf(t4.z, pz, t4.w))));
        m1 = fminf(m1, fmaf(t5.x, px, fmaf(t5.y, py, fmaf(t5.z, pz, t5.w))));
        m2 = fminf(m2, fmaf(t6.x, px, fmaf(t6.y, py, fmaf(t6.z, pz, t6.w))));
        m3 = fminf(m3, fmaf(t7.x, px, fmaf(t7.y, py, fmaf(t7.z, pz, t7.w))));
    }
    float v = fminf(fminf(m0, m1), fminf(m2, m3)) + p2;

    for (int off = 32; off > 0; off >>= 1)
        v += __shfl_down(v, off, 64);

    __syncthreads();
    float* red = (float*)sOpp;
    if ((tid & 63) == 0) red[tid >> 6] = v;
    __syncthreads();
    if (tid == 0) {
        float s = (red[0] + red[1]) + (red[2] + red[3]);
        atomicAdd(out, s * (1.0f / ((float)B_SZ * (float)NPTS)));
    }
}

extern "C" void kernel_launch(void* const* d_in, const int* in_sizes, int n_in,
                              void* d_out, int out_size, void* d_ws, size_t ws_size,
                              hipStream_t stream) {
    const float* pred   = (const float*)d_in[0];
    const float* target = (const float*)d_in[1];
    float* out = (float*)d_out;

    hipMemsetAsync(out, 0, sizeof(float), stream);

    const size_t rowBytes  = (size_t)NQ  * NRT * sizeof(float);    // 1 MB
    const size_t colABytes = (size_t)NRT * sizeof(unsigned);       // 256 KB
    const size_t colPBytes = (size_t)NCH * NRT * sizeof(unsigned); // 4 MB
    if (ws_size >= rowBytes + colPBytes) {
        // contention-free slice mode (R12/R15 counters: ws is ~268 MB)
        float*    wsRow     = (float*)d_ws;
        unsigned* wsColPart = (unsigned*)((char*)d_ws + rowBytes);
        chamfer_mfma<<<B_SZ * NCH * NQ, MBLK, 0, stream>>>(
            pred, target, wsRow, nullptr, wsColPart);
        chamfer_combine<<<(2 * NRT) / BLK, BLK, 0, stream>>>(
            wsRow, nullptr, wsColPart, out);
    } else if (ws_size >= rowBytes + colABytes) {
        // atomic fallback (R15-passing behavior)
        float*    wsRow = (float*)d_ws;
        unsigned* wsCol = (unsigned*)((char*)d_ws + rowBytes);
        hipMemsetAsync(wsCol, 0x7F, colABytes, stream);
        chamfer_mfma<<<B_SZ * NCH * NQ, MBLK, 0, stream>>>(
            pred, target, wsRow, wsCol, nullptr);
        chamfer_combine<<<(2 * NRT) / BLK, BLK, 0, stream>>>(
            wsRow, wsCol, nullptr, out);
    } else {
        dim3 grid(B_SZ * (NPTS / BLK), 2);
        chamfer_kernel<<<grid, BLK, 0, stream>>>(pred, target, out);
    }
}

// Round 17
// 48.050 us; speedup vs baseline: 2.8547x; 1.3144x over previous
//
#include <hip/hip_runtime.h>

typedef __attribute__((ext_vector_type(8)))  short short8;
typedef __attribute__((ext_vector_type(16))) float f32x16;

#define B_SZ  16
#define NPTS  4096
#define MBLK  256                   // 4 waves
#define PRB   256                   // pred rows per block (64/wave, 2x32 frags)
#define NFR   2
#define NCH   (NPTS / PRB)          // 16 row-chunks
#define NHALF 4                     // target quarters per (dir,b,chunk)  [R12: 2]
#define TPB_T (NPTS / NHALF)        // 1024 targets scanned per block
#define STGT  512                   // targets per LDS stage
#define STILE (STGT / 32)           // 16 tiles per stage
#define NSTG  (TPB_T / STGT)        // 2 stages
#define TOT   (2 * B_SZ * NPTS)     // 131072
#define BLK   256

__device__ __forceinline__ unsigned short f2bf(float f) {
    unsigned u = __float_as_uint(f);
    return (unsigned short)((u + 0x7FFFu + ((u >> 16) & 1u)) >> 16);
}
__device__ __forceinline__ float bf2f(unsigned short s) {
    return __uint_as_float(((unsigned)s) << 16);
}
__device__ __forceinline__ short n2(unsigned short s) {
    return (short)f2bf(-2.0f * bf2f(s));
}
// NOTE: no min3f inline-asm. R10/R13/R14 (asm min3 on MFMA results) failed;
// fminf-only rounds (R9/R11/R12/R15/R16) all passed. Never reintroduce.

// ---------------------------------------------------------------------------
// R12-proven two-pass split-precision chamfer (session-best 45.6 us, absmax
// 0.0). THIS ROUND CHANGES ONLY NHALF 2->4: finer target decomposition ->
// grid 2048 blocks = 8 blocks/CU requested (R12 was 4) to lift occupancy
// past the ~31% / 4-waves-per-SIMD plateau. All code paths verbatim:
//  slot algebra s0-2:-2ph·th s3-5:-2pl·th s6-8:-2ph·tl s9-11:-2pl·tl
//  s12,13:p2h,p2l s14,15:t2h,t2l ; 32x32x16 MFMA; probe-guarded layout;
//  shfl row fold + label write; label-indexed atomicMin slow path.
// ---------------------------------------------------------------------------
__global__ __launch_bounds__(MBLK, 2) void chamfer_mfma(
    const float* __restrict__ pred, const float* __restrict__ target,
    float* __restrict__ ws)
{
    __shared__ short8   sB[STILE * 64];   // 16 KB B fragments
    __shared__ unsigned rowLds[MBLK];     // slow-path row mins only

    const int dir = blockIdx.y;
    const float* own = dir ? target : pred;
    const float* opp = dir ? pred : target;

    const int bx    = blockIdx.x;               // [0, 1024)
    const int b     = bx / (NCH * NHALF);       // 64 blocks per batch
    const int chunk = (bx / NHALF) & (NCH - 1);
    const int half  = bx & (NHALF - 1);
    const int tid   = threadIdx.x;
    const int lane  = tid & 63;
    const int w     = tid >> 6;
    const int r32   = lane & 31;
    const int h     = lane >> 5;
    const short ONE = (short)0x3F80;

    // ---- A fragments: 2 x 32 own rows per wave (R12 verbatim) ----
    short8 af[NFR];
    #pragma unroll
    for (int f = 0; f < NFR; ++f) {
        const float* pp = own +
            ((size_t)b*NPTS + chunk*PRB + w*64 + f*32 + r32)*3;
        float x = pp[0], y = pp[1], z = pp[2];
        unsigned short phx=f2bf(x), phy=f2bf(y), phz=f2bf(z);
        unsigned short plx=f2bf(x-bf2f(phx)), ply=f2bf(y-bf2f(phy)),
                       plz=f2bf(z-bf2f(phz));
        short8 v;
        if (h == 0) {
            v[0]=n2(phx); v[1]=n2(phy); v[2]=n2(phz);
            v[3]=n2(plx); v[4]=n2(ply); v[5]=n2(plz);
            v[6]=n2(phx); v[7]=n2(phy);
        } else {
            float p2 = fmaf(z,z,fmaf(y,y,x*x));
            unsigned short p2h=f2bf(p2), p2l=f2bf(p2-bf2f(p2h));
            v[0]=n2(phz); v[1]=n2(plx); v[2]=n2(ply); v[3]=n2(plz);
            v[4]=(short)p2h; v[5]=(short)p2l; v[6]=ONE; v[7]=ONE;
        }
        af[f] = v;
    }

    // ---- layout probe: D(lane,reg) = true row label under ANY layout ----
    f32x16 zc;
    #pragma unroll
    for (int r = 0; r < 16; ++r) zc[r] = 0.0f;
    short8 mA = {0,0,0,0,0,0,0,0}, mB = {0,0,0,0,0,0,0,0};
    if (h == 0) { mA[0] = (short)f2bf((float)r32); mB[0] = ONE; }
    f32x16 pr = __builtin_amdgcn_mfma_f32_32x32x16_bf16(mA, mB, zc, 0, 0, 0);
    int lab[16];
    bool ok = true;
    #pragma unroll
    for (int r = 0; r < 16; ++r) {
        lab[r] = ((int)(pr[r] + 0.5f)) & 31;
        ok = ok && (lab[r] == ((r & 3) + 8 * (r >> 2) + 4 * h));
    }
    const bool fast = __all(ok) != 0;

    // ---- scan this block's 1024 targets in 2 staged passes ----
    f32x16 rmin0, rmin1;
    #pragma unroll
    for (int r = 0; r < 16; ++r) { rmin0[r] = 1e30f; rmin1[r] = 1e30f; }

    const float* oppB = opp + ((size_t)b * NPTS + half * TPB_T) * 3;

    for (int s = 0; s < NSTG; ++s) {
        __syncthreads();   // previous stage's compute done
        #pragma unroll
        for (int i = 0; i < (STILE*64)/MBLK; ++i) {   // 4 entries/thread
            int e  = i * MBLK + tid;
            int t  = e >> 6, l2 = e & 63;
            int cc = l2 & 31, hh = l2 >> 5;
            const float* o = oppB + (size_t)(s*STGT + t*32 + cc)*3;
            float tx=o[0], ty=o[1], tz=o[2];
            unsigned short hx=f2bf(tx), hy=f2bf(ty), hz=f2bf(tz);
            unsigned short lx=f2bf(tx-bf2f(hx)), ly=f2bf(ty-bf2f(hy)),
                           lz=f2bf(tz-bf2f(hz));
            short8 v;
            if (hh == 0) {
                v[0]=(short)hx; v[1]=(short)hy; v[2]=(short)hz;
                v[3]=(short)hx; v[4]=(short)hy; v[5]=(short)hz;
                v[6]=(short)lx; v[7]=(short)ly;
            } else {
                float t2 = fmaf(tz,tz,fmaf(ty,ty,tx*tx));
                unsigned short t2h=f2bf(t2), t2l=f2bf(t2-bf2f(t2h));
                v[0]=(short)lz; v[1]=(short)lx; v[2]=(short)ly;
                v[3]=(short)lz; v[4]=ONE; v[5]=ONE;
                v[6]=(short)t2h; v[7]=(short)t2l;
            }
            sB[e] = v;   // contiguous 16B/thread
        }
        __syncthreads();

        for (int t = 0; t < STILE; ++t) {
            short8 b0 = sB[t*64 + lane];
            f32x16 a0 = __builtin_amdgcn_mfma_f32_32x32x16_bf16(af[0], b0, zc, 0,0,0);
            f32x16 a1 = __builtin_amdgcn_mfma_f32_32x32x16_bf16(af[1], b0, zc, 0,0,0);
            #pragma unroll
            for (int r = 0; r < 16; ++r) {
                rmin0[r] = fminf(a0[r], rmin0[r]);
                rmin1[r] = fminf(a1[r], rmin1[r]);
            }
        }
    }

    // ---- epilogue (R12 verbatim): per-row shfl fold, write by LABEL ----
    float* wr = ws + (size_t)half * TOT
                   + ((size_t)dir * B_SZ + b) * NPTS + chunk * PRB;
    if (fast) {
        #pragma unroll
        for (int r = 0; r < 16; ++r) {
            float v0 = rmin0[r];
            v0 = fminf(v0, __shfl_xor(v0, 1, 64));
            v0 = fminf(v0, __shfl_xor(v0, 2, 64));
            v0 = fminf(v0, __shfl_xor(v0, 4, 64));
            v0 = fminf(v0, __shfl_xor(v0, 8, 64));
            v0 = fminf(v0, __shfl_xor(v0, 16, 64));
            float v1 = rmin1[r];
            v1 = fminf(v1, __shfl_xor(v1, 1, 64));
            v1 = fminf(v1, __shfl_xor(v1, 2, 64));
            v1 = fminf(v1, __shfl_xor(v1, 4, 64));
            v1 = fminf(v1, __shfl_xor(v1, 8, 64));
            v1 = fminf(v1, __shfl_xor(v1, 16, 64));
            if (r32 == 0) {
                wr[w*64 +  0 + lab[r]] = v0;
                wr[w*64 + 32 + lab[r]] = v1;
            }
        }
    } else {
        rowLds[tid] = 0x7F7F7F7Fu;
        __syncthreads();
        #pragma unroll
        for (int r = 0; r < 16; ++r) {
            atomicMin(&rowLds[w*64 +  0 + lab[r]],
                      __float_as_uint(fmaxf(rmin0[r], 0.0f)));
            atomicMin(&rowLds[w*64 + 32 + lab[r]],
                      __float_as_uint(fmaxf(rmin1[r], 0.0f)));
        }
        __syncthreads();
        wr[tid] = __uint_as_float(rowLds[tid]);
    }
}

// -------- combine: min over the 4 quarters, then mean-reduce -----------------
__global__ __launch_bounds__(BLK) void chamfer_combine(
    const float* __restrict__ ws, float* __restrict__ out)
{
    const int idx = blockIdx.x * BLK + threadIdx.x;   // 0 .. TOT-1
    float v = fminf(fminf(ws[idx],           ws[TOT + idx]),
                    fminf(ws[2*TOT + idx],   ws[3*TOT + idx]));

    for (int off = 32; off > 0; off >>= 1)
        v += __shfl_down(v, off, 64);

    __shared__ float red[4];
    const int tid = threadIdx.x;
    if ((tid & 63) == 0) red[tid >> 6] = v;
    __syncthreads();
    if (tid == 0) {
        float s = (red[0] + red[1]) + (red[2] + red[3]);
        atomicAdd(out, s * (1.0f / ((float)B_SZ * (float)NPTS)));
    }
}

// ---------------- fallback (round-1 kernel) if ws too small ------------------
__global__ __launch_bounds__(BLK) void chamfer_kernel(
    const float* __restrict__ pred, const float* __restrict__ target,
    float* __restrict__ out)
{
    __shared__ float4 sOpp[NPTS];

    const int dir = blockIdx.y;
    const float* own = (dir == 0) ? pred : target;
    const float* opp = (dir == 0) ? target : pred;

    const int b     = blockIdx.x >> 4;
    const int chunk = blockIdx.x & 15;
    const int tid   = threadIdx.x;

    const float* oppB = opp + (size_t)b * NPTS * 3;
    for (int j = tid; j < NPTS; j += BLK) {
        float x = oppB[3 * j + 0];
        float y = oppB[3 * j + 1];
        float z = oppB[3 * j + 2];
        sOpp[j] = make_float4(-2.0f * x, -2.0f * y, -2.0f * z,
                              fmaf(z, z, fmaf(y, y, x * x)));
    }
    __syncthreads();

    const int i = chunk * BLK + tid;
    const float* op = own + ((size_t)b * NPTS + i) * 3;
    const float px = op[0], py = op[1], pz = op[2];
    const float p2 = fmaf(pz, pz, fmaf(py, py, px * px));

    float m0 = 1e30f, m1 = 1e30f, m2 = 1e30f, m3 = 1e30f;
    for (int j = 0; j < NPTS; j += 8) {
        float4 t0 = sOpp[j + 0];
        float4 t1 = sOpp[j + 1];
        float4 t2 = sOpp[j + 2];
        float4 t3 = sOpp[j + 3];
        float4 t4 = sOpp[j + 4];
        float4 t5 = sOpp[j + 5];
        float4 t6 = sOpp[j + 6];
        float4 t7 = sOpp[j + 7];
        m0 = fminf(m0, fmaf(t0.x, px, fmaf(t0.y, py, fmaf(t0.z, pz, t0.w))));
        m1 = fminf(m1, fmaf(t1.x, px, fmaf(t1.y, py, fmaf(t1.z, pz, t1.w))));
        m2 = fminf(m2, fmaf(t2.x, px, fmaf(t2.y, py, fmaf(t2.z, pz, t2.w))));
        m3 = fminf(m3, fmaf(t3.x, px, fmaf(t3.y, py, fmaf(t3.z, pz, t3.w))));
        m0 = fminf(m0, fmaf(t4.x, px, fmaf(t4.y, py, fmaf(t4.z, pz, t4.w))));
        m1 = fminf(m1, fmaf(t5.x, px, fmaf(t5.y, py, fmaf(t5.z, pz, t5.w))));
        m2 = fminf(m2, fmaf(t6.x, px, fmaf(t6.y, py, fmaf(t6.z, pz, t6.w))));
        m3 = fminf(m3, fmaf(t7.x, px, fmaf(t7.y, py, fmaf(t7.z, pz, t7.w))));
    }
    float v = fminf(fminf(m0, m1), fminf(m2, m3)) + p2;

    for (int off = 32; off > 0; off >>= 1)
        v += __shfl_down(v, off, 64);

    __syncthreads();
    float* red = (float*)sOpp;
    if ((tid & 63) == 0) red[tid >> 6] = v;
    __syncthreads();
    if (tid == 0) {
        float s = (red[0] + red[1]) + (red[2] + red[3]);
        atomicAdd(out, s * (1.0f / ((float)B_SZ * (float)NPTS)));
    }
}

extern "C" void kernel_launch(void* const* d_in, const int* in_sizes, int n_in,
                              void* d_out, int out_size, void* d_ws, size_t ws_size,
                              hipStream_t stream) {
    const float* pred   = (const float*)d_in[0];
    const float* target = (const float*)d_in[1];
    float* out = (float*)d_out;

    hipMemsetAsync(out, 0, sizeof(float), stream);

    const size_t ws_needed = (size_t)NHALF * TOT * sizeof(float);  // 2 MB
    if (ws_size >= ws_needed) {
        float* ws = (float*)d_ws;
        dim3 grid1(B_SZ * NCH * NHALF, 2);         // 1024 x 2 = 2048 blocks
        chamfer_mfma<<<grid1, MBLK, 0, stream>>>(pred, target, ws);
        chamfer_combine<<<TOT / BLK, BLK, 0, stream>>>(ws, out);
    } else {
        dim3 grid(B_SZ * (NPTS / BLK), 2);
        chamfer_kernel<<<grid, BLK, 0, stream>>>(pred, target, out);
    }
}